// Round 18
// baseline (399.373 us; speedup 1.0000x reference)
//
#include <hip/hip_runtime.h>
#include <hip/hip_bf16.h>

#define B_ 32
#define T_ 2048
#define D_ 1024
#define N_ 1024
#define M_ (B_*T_)

#define BM 64
#define BN 128
#define BK 32
#define NTSPLIT 2                  // two disjoint score-partial buffers, summed in k3
#define NTP (N_ / BN / NTSPLIT)    // 4 nt-passes per block
#define NSTEP (NTP * (D_ / BK))    // 128 flat steps (nt,kt)

typedef short bf16x8 __attribute__((ext_vector_type(8)));
typedef float f32x4 __attribute__((ext_vector_type(4)));
typedef unsigned short us4 __attribute__((ext_vector_type(4)));

__device__ __forceinline__ unsigned short bf16_rn(float x) {
    unsigned u = __float_as_uint(x);
    u += 0x7FFFu + ((u >> 16) & 1u);
    return (unsigned short)(u >> 16);
}

__device__ __forceinline__ void gload_lds16(const void* g, void* l) {
    __builtin_amdgcn_global_load_lds(
        (__attribute__((address_space(1))) void*)(g),
        (__attribute__((address_space(3))) void*)(l), 16, 0, 0);
}

#define FENCE() asm volatile("" ::: "memory")
#define RAW_BARRIER() do { FENCE(); __builtin_amdgcn_s_barrier(); FENCE(); } while (0)

// K_prep: small prologue (R15/R17-verified bodies, one launch).
//   blocks [0,1024):    W2 [D][N] -> W2T bf16 [N][D]
//   blocks [1024,1152): qp[b][n] = query@W1 + b1
__global__ void k_prep(const float* __restrict__ W2, unsigned short* __restrict__ Th,
                       const float* __restrict__ query, const float* __restrict__ W1,
                       const float* __restrict__ b1, float* __restrict__ qp) {
    __shared__ float tile[32][33];
    const int blk = blockIdx.x;
    const int tid = threadIdx.x;

    if (blk < 1024) {
        int n0 = (blk & 31) * 32, d0 = (blk >> 5) * 32;
        int tx = tid & 31, ty = tid >> 5; // 32 x 8
        #pragma unroll
        for (int i = 0; i < 4; i++) {
            int d = d0 + ty + i * 8;
            tile[ty + i * 8][tx] = W2[d * N_ + n0 + tx];
        }
        __syncthreads();
        #pragma unroll
        for (int i = 0; i < 4; i++) {
            int n = n0 + ty + i * 8;
            Th[n * D_ + d0 + tx] = bf16_rn(tile[tx][ty + i * 8]);
        }
    } else {
        int t = blk - 1024;           // 0..127
        int b = t & 31;
        int n = (t >> 5) * 256 + tid; // 4 n-chunks of 256
        const float* q = query + b * D_;
        const float* w = W1 + n;
        float s = 0.f;
        #pragma unroll 8
        for (int d = 0; d < D_; d++) s += q[d] * w[d * N_];
        qp[b * N_ + n] = s + b1[n];
    }
}

// K0v: values [M][D] fp32 -> Av bf16 (RTN), vectorized grid-stride (R15 body)
__global__ void k0_vals(const float* __restrict__ v,
                        unsigned short* __restrict__ o) {
    size_t i = ((size_t)blockIdx.x * 256 + threadIdx.x) * 8;
    const size_t stride = (size_t)gridDim.x * 256 * 8;
    for (; i < (size_t)M_ * D_; i += stride) {
        float4 a = *(const float4*)(v + i);
        float4 b = *(const float4*)(v + i + 4);
        us4 h0, h1;
        h0[0] = bf16_rn(a.x); h0[1] = bf16_rn(a.y);
        h0[2] = bf16_rn(a.z); h0[3] = bf16_rn(a.w);
        h1[0] = bf16_rn(b.x); h1[1] = bf16_rn(b.y);
        h1[2] = bf16_rn(b.z); h1[3] = bf16_rn(b.w);
        *(us4*)(o + i) = h0;
        *(us4*)(o + i + 4) = h1;
    }
}

// k2 staging for flat step u (BK=32): B 2 + A 1 gload_lds per thread.
// LDS phys layout per tile: [rows][4 chunks of 16B]; phys chunk (r, j)
// holds source chunk j ^ (r&3) ^ ((r>>2)&3) (2-way bank spread on b128
// frag reads at 64B row stride). Sources pre-swizzled; dests wave-uniform.
__device__ __forceinline__ void k2_stage(int u, unsigned short* sa, unsigned short* sb,
                                         int m0, int nt0, int wid, int lane,
                                         const unsigned short* __restrict__ Av,
                                         const unsigned short* __restrict__ W2Th) {
    const int nt = nt0 + (u >> 5);
    const int k0 = (u & 31) * BK;
    const int rl4 = lane >> 2;   // row within 16-row group
    const int j4 = lane & 3;     // phys chunk
    #pragma unroll
    for (int i = 0; i < 2; i++) {
        int r = wid * 32 + i * 16 + rl4;
        int jj = j4 ^ (r & 3) ^ ((r >> 2) & 3);
        size_t soff = (size_t)(nt * BN + r) * D_ + k0 + jj * 8;
        gload_lds16(W2Th + soff, &sb[(wid * 32 + i * 16) * 32]);
    }
    {
        int r = wid * 16 + rl4;
        int jj = j4 ^ (r & 3) ^ ((r >> 2) & 3);
        size_t soff = (size_t)(m0 + r) * D_ + k0 + jj * 8;
        gload_lds16(Av + soff, &sa[(wid * 16) * 32]);
    }
}

// K2: fused score GEMM partial, counted-vmcnt triple-buffer schedule.
// R11-verified geometry (64x128 tile, 4 waves 2Mx2N, acc[2][4]=32 AGPR,
// Av bf16 staging, XCD-pairing swizzle, disjoint partial store) at BK=32:
// 12 KB/buffer x3 = 36.9 KB LDS -> 4 blocks/CU (R3's schedule WITHOUT its
// confounds: no cvt, no ds_write, no fp32-A conflicts, no 1-block/CU LDS).
// Steady state: stage(s+2) issued, compute(s), vmcnt(3) [s+1's 3 loads
// landed; s+2's 3 in flight], raw s_barrier publishes. Tail: vmcnt(0).
__global__ __launch_bounds__(256, 2) void k2_score(
    const unsigned short* __restrict__ Av,
    const unsigned short* __restrict__ W2Th,
    const float* __restrict__ qp,
    const float* __restrict__ b2,
    const float* __restrict__ V,
    float* __restrict__ scorep) {
    __shared__ unsigned short sA[3][BM * BK];   // 3 x 4 KB
    __shared__ unsigned short sB[3][BN * BK];   // 3 x 8 KB
    __shared__ float red[2 * BM];

    const int tid = threadIdx.x;
    const int lane = tid & 63;
    const int wid = tid >> 6;
    const int wm = wid >> 1, wn = wid & 1;    // wave tile 32x64
    const int g = lane >> 4, c16 = lane & 15;

    // XCD-pairing swizzle: bid -> wgid (bit rotation, bijective on [0,2048))
    const int bid = blockIdx.x;
    const int wgid = ((bid & 7) << 8) | (bid >> 3);
    const int m0 = (wgid >> 1) * BM;
    const int b = m0 >> 11; // m0 / T_
    const int half = wgid & 1;
    const int nt0 = half * NTP;

    float rowpart[8];
    #pragma unroll
    for (int i = 0; i < 8; i++) rowpart[i] = 0.f;

    f32x4 acc[2][4];
    #pragma unroll
    for (int mi = 0; mi < 2; mi++)
        #pragma unroll
        for (int ni = 0; ni < 4; ni++) {
            f32x4 z = {0.f, 0.f, 0.f, 0.f};
            acc[mi][ni] = z;
        }

    // buffer rotation via pointer swap (no runtime-indexed arrays)
    unsigned short *a0 = sA[0], *a1 = sA[1], *a2 = sA[2];
    unsigned short *b0 = sB[0], *b1 = sB[1], *b2p = sB[2];

    // prologue: stage steps 0 and 1 (3 loads each)
    k2_stage(0, a0, b0, m0, nt0, wid, lane, Av, W2Th);
    k2_stage(1, a1, b1, m0, nt0, wid, lane, Av, W2Th);
    asm volatile("s_waitcnt vmcnt(3)" ::: "memory"); // step 0 landed
    RAW_BARRIER();

    for (int s = 0; s < NSTEP; ++s) {
        if (s + 2 < NSTEP)
            k2_stage(s + 2, a2, b2p, m0, nt0, wid, lane, Av, W2Th);

        // compute step s from (a0, b0): one phase, 8 MFMA
        {
            bf16x8 aH[2], bH[4];
            #pragma unroll
            for (int mi = 0; mi < 2; mi++) {
                int r = wm * 32 + mi * 16 + c16;
                int ch = g ^ (r & 3) ^ ((r >> 2) & 3);
                aH[mi] = *(const bf16x8*)&a0[r * 32 + ch * 8];
            }
            #pragma unroll
            for (int ni = 0; ni < 4; ni++) {
                int r = wn * 64 + ni * 16 + c16;
                int ch = g ^ (r & 3) ^ ((r >> 2) & 3);
                bH[ni] = *(const bf16x8*)&sB[0][0]; // placeholder overwritten below
                bH[ni] = *(const bf16x8*)&b0[r * 32 + ch * 8];
            }
            #pragma unroll
            for (int mi = 0; mi < 2; mi++)
                #pragma unroll
                for (int ni = 0; ni < 4; ni++)
                    acc[mi][ni] = __builtin_amdgcn_mfma_f32_16x16x32_bf16(aH[mi], bH[ni], acc[mi][ni], 0, 0, 0);
        }

        // nt-pass epilogue every 32 steps: fold acc via tanh, reset acc
        if ((s & 31) == 31) {
            int nt = nt0 + (s >> 5);
            #pragma unroll
            for (int ni = 0; ni < 4; ni++) {
                int n = nt * BN + wn * 64 + ni * 16 + c16;
                float qv = qp[b * N_ + n] + b2[n];
                float Vv = V[n];
                #pragma unroll
                for (int mi = 0; mi < 2; mi++)
                    #pragma unroll
                    for (int r = 0; r < 4; r++)
                        rowpart[mi * 4 + r] += tanhf(acc[mi][ni][r] + qv) * Vv;
            }
            #pragma unroll
            for (int mi = 0; mi < 2; mi++)
                #pragma unroll
                for (int ni = 0; ni < 4; ni++) {
                    f32x4 z = {0.f, 0.f, 0.f, 0.f};
                    acc[mi][ni] = z;
                }
        }

        // counted drain: s+1's tile landed (3 newest = s+2's loads may fly)
        if (s + 2 < NSTEP) {
            asm volatile("s_waitcnt vmcnt(3)" ::: "memory");
        } else if (s + 1 < NSTEP) {
            asm volatile("s_waitcnt vmcnt(0)" ::: "memory");
        }
        RAW_BARRIER();

        // rotate buffers
        unsigned short* t0 = a0; a0 = a1; a1 = a2; a2 = t0;
        unsigned short* t1 = b0; b0 = b1; b1 = b2p; b2p = t1;
    }

    // reduce across the 16 n-lanes of each group
    #pragma unroll
    for (int i = 0; i < 8; i++) {
        float v = rowpart[i];
        v += __shfl_xor(v, 1);
        v += __shfl_xor(v, 2);
        v += __shfl_xor(v, 4);
        v += __shfl_xor(v, 8);
        rowpart[i] = v;
    }
    if (c16 == 0) {
        #pragma unroll
        for (int mi = 0; mi < 2; mi++)
            #pragma unroll
            for (int r = 0; r < 4; r++)
                red[wn * BM + wm * 32 + mi * 16 + g * 4 + r] = rowpart[mi * 4 + r];
    }
    __syncthreads();
    if (tid < BM) {
        // plain store to this half's disjoint partial buffer (no atomics)
        scorep[(size_t)half * M_ + m0 + tid] = red[tid] + red[BM + tid];
    }
}

// K3: softmax over T per batch (sums the two score partials, softmaxes,
// writes weights) + zeros this batch's ctx slice (replaces memsetAsync).
__global__ void k3_softmax(const float* __restrict__ sp,
                           float* __restrict__ sw,
                           float* __restrict__ ctx) {
    int b = blockIdx.x;
    const float* r0 = sp + b * T_;
    const float* r1 = sp + M_ + b * T_;
    float* row = sw + b * T_;
    int tid = threadIdx.x;

    #pragma unroll
    for (int i = 0; i < 4; i++) ctx[b * D_ + tid + i * 256] = 0.f;

    float v[8];
    float lmax = -1e30f;
    #pragma unroll
    for (int i = 0; i < 8; i++) {
        int idx = tid + i * 256;
        v[i] = r0[idx] + r1[idx];
        lmax = fmaxf(lmax, v[i]);
    }
    #pragma unroll
    for (int d = 1; d < 64; d <<= 1) lmax = fmaxf(lmax, __shfl_xor(lmax, d));
    __shared__ float sm[4], ss[4];
    if ((tid & 63) == 0) sm[tid >> 6] = lmax;
    __syncthreads();
    lmax = fmaxf(fmaxf(sm[0], sm[1]), fmaxf(sm[2], sm[3]));
    float lsum = 0.f;
    #pragma unroll
    for (int i = 0; i < 8; i++) {
        v[i] = expf(v[i] - lmax);
        lsum += v[i];
    }
    #pragma unroll
    for (int d = 1; d < 64; d <<= 1) lsum += __shfl_xor(lsum, d);
    if ((tid & 63) == 0) ss[tid >> 6] = lsum;
    __syncthreads();
    lsum = ss[0] + ss[1] + ss[2] + ss[3];
    float inv = 1.f / lsum;
    #pragma unroll
    for (int i = 0; i < 8; i++) row[tid + i * 256] = v[i] * inv;
}

// K4: context[b][d] += partial over t-slice, reading bf16 Av (half traffic).
// (atomic; ctx zeroed by k3)
__global__ void k4_context(const unsigned short* __restrict__ Av,
                           const float* __restrict__ w,
                           float* __restrict__ ctx) {
    int b = blockIdx.x;
    int dc = blockIdx.y;           // 8 chunks of 128 d
    int tc = blockIdx.z;           // 8 chunks of 256 t
    int d4 = threadIdx.x & 31;
    int th = threadIdx.x >> 5;     // 8 t-slices of 32
    const float* wrow = w + b * T_;
    int d = dc * 128 + d4 * 4;
    const unsigned short* vbase = Av + (size_t)b * T_ * D_ + d;
    float4 acc = {0.f, 0.f, 0.f, 0.f};
    int t0 = tc * 256 + th * 32;
    for (int t = t0; t < t0 + 32; t++) {
        float wt = wrow[t];
        us4 hv = *(const us4*)(vbase + (size_t)t * D_);
        acc.x += wt * __uint_as_float((unsigned)hv[0] << 16);
        acc.y += wt * __uint_as_float((unsigned)hv[1] << 16);
        acc.z += wt * __uint_as_float((unsigned)hv[2] << 16);
        acc.w += wt * __uint_as_float((unsigned)hv[3] << 16);
    }
    __shared__ float4 red4[256];
    red4[threadIdx.x] = acc;
    __syncthreads();
    if (th == 0) {
        float4 s = red4[d4];
        #pragma unroll
        for (int i = 1; i < 8; i++) {
            float4 o = red4[i * 32 + d4];
            s.x += o.x; s.y += o.y; s.z += o.z; s.w += o.w;
        }
        atomicAdd(&ctx[b * D_ + d + 0], s.x);
        atomicAdd(&ctx[b * D_ + d + 1], s.y);
        atomicAdd(&ctx[b * D_ + d + 2], s.z);
        atomicAdd(&ctx[b * D_ + d + 3], s.w);
    }
}

extern "C" void kernel_launch(void* const* d_in, const int* in_sizes, int n_in,
                              void* d_out, int out_size, void* d_ws, size_t ws_size,
                              hipStream_t stream) {
    const float* query  = (const float*)d_in[0];
    const float* values = (const float*)d_in[1];
    const float* W1     = (const float*)d_in[2];
    const float* b1     = (const float*)d_in[3];
    const float* W2     = (const float*)d_in[4];
    const float* b2     = (const float*)d_in[5];
    const float* V      = (const float*)d_in[6];
    // d_in[7] = bV: unused — softmax is shift-invariant, bV affects neither output.

    float* ctx = (float*)d_out;                 // [B, D]
    float* weights = (float*)d_out + B_ * D_;   // [B, T]: written by k3 only

    // ws: W2T (2 MB) | q_proj (128 KB) | score partials (512 KB) | Av bf16 (128 MB)
    size_t need = (size_t)N_ * D_ * sizeof(unsigned short)
                + (size_t)B_ * N_ * sizeof(float)
                + (size_t)NTSPLIT * M_ * sizeof(float)
                + (size_t)M_ * D_ * sizeof(unsigned short);
    if (ws_size < need) return;
    unsigned short* Th = (unsigned short*)d_ws;
    float* qp = (float*)(Th + (size_t)N_ * D_);
    float* scorep = qp + (size_t)B_ * N_;
    unsigned short* Av = (unsigned short*)(scorep + (size_t)NTSPLIT * M_);

    k_prep<<<1152, 256, 0, stream>>>(W2, Th, query, W1, b1, qp);
    k0_vals<<<2048, 256, 0, stream>>>(values, Av);
    k2_score<<<(M_ / BM) * NTSPLIT, 256, 0, stream>>>(Av, Th, qp, b2, V, scorep);
    k3_softmax<<<B_, 256, 0, stream>>>(scorep, weights, ctx);
    k4_context<<<dim3(B_, 8, 8), 256, 0, stream>>>(Av, weights, ctx);
}

// Round 19
// 351.584 us; speedup vs baseline: 1.1359x; 1.1359x over previous
//
#include <hip/hip_runtime.h>
#include <hip/hip_bf16.h>

#define B_ 32
#define T_ 2048
#define D_ 1024
#define N_ 1024
#define M_ (B_*T_)

#define BM 64
#define BN 128
#define BK 64
#define NTSPLIT 2                  // two disjoint score-partial buffers
#define NTP (N_ / BN / NTSPLIT)    // 4 nt-passes per block

typedef short bf16x8 __attribute__((ext_vector_type(8)));
typedef float f32x4 __attribute__((ext_vector_type(4)));
typedef unsigned short us4 __attribute__((ext_vector_type(4)));

__device__ __forceinline__ unsigned short bf16_rn(float x) {
    unsigned u = __float_as_uint(x);
    u += 0x7FFFu + ((u >> 16) & 1u);
    return (unsigned short)(u >> 16);
}

__device__ __forceinline__ void gload_lds16(const void* g, void* l) {
    __builtin_amdgcn_global_load_lds(
        (__attribute__((address_space(1))) void*)(g),
        (__attribute__((address_space(3))) void*)(l), 16, 0, 0);
}

// K_prep: fused prologue (R15-verified bodies), one launch.
//   blocks [0,2048):    values fp32 -> Av bf16 (RTN)
//   blocks [2048,3072): W2 [D][N] -> W2T bf16 [N][D]
//   blocks [3072,3200): qp[b][n] = query@W1 + b1
//   blocks [3200,3232): zero ctx[b][:] (replaces memsetAsync; k4 accumulates)
__global__ void k_prep(const float* __restrict__ values, unsigned short* __restrict__ Av,
                       const float* __restrict__ W2, unsigned short* __restrict__ Th,
                       const float* __restrict__ query, const float* __restrict__ W1,
                       const float* __restrict__ b1, float* __restrict__ qp,
                       float* __restrict__ ctx) {
    __shared__ float tile[32][33];
    const int blk = blockIdx.x;
    const int tid = threadIdx.x;

    if (blk < 2048) {
        size_t base = (size_t)blk * 32768 + (size_t)tid * 8;
        #pragma unroll 4
        for (int it = 0; it < 16; ++it) {
            size_t i = base + (size_t)it * 2048;
            float4 a = *(const float4*)(values + i);
            float4 b = *(const float4*)(values + i + 4);
            us4 h0, h1;
            h0[0] = bf16_rn(a.x); h0[1] = bf16_rn(a.y);
            h0[2] = bf16_rn(a.z); h0[3] = bf16_rn(a.w);
            h1[0] = bf16_rn(b.x); h1[1] = bf16_rn(b.y);
            h1[2] = bf16_rn(b.z); h1[3] = bf16_rn(b.w);
            *(us4*)(Av + i) = h0;
            *(us4*)(Av + i + 4) = h1;
        }
    } else if (blk < 3072) {
        int t = blk - 2048;
        int n0 = (t & 31) * 32, d0 = (t >> 5) * 32;
        int tx = tid & 31, ty = tid >> 5; // 32 x 8
        #pragma unroll
        for (int i = 0; i < 4; i++) {
            int d = d0 + ty + i * 8;
            tile[ty + i * 8][tx] = W2[d * N_ + n0 + tx];
        }
        __syncthreads();
        #pragma unroll
        for (int i = 0; i < 4; i++) {
            int n = n0 + ty + i * 8;
            Th[n * D_ + d0 + tx] = bf16_rn(tile[tx][ty + i * 8]);
        }
    } else if (blk < 3200) {
        int t = blk - 3072;           // 0..127
        int b = t & 31;
        int n = (t >> 5) * 256 + tid; // 4 n-chunks of 256
        const float* q = query + b * D_;
        const float* w = W1 + n;
        float s = 0.f;
        #pragma unroll 8
        for (int d = 0; d < D_; d++) s += q[d] * w[d * N_];
        qp[b * N_ + n] = s + b1[n];
    } else {
        int b = blk - 3200;           // 0..31
        #pragma unroll
        for (int i = 0; i < 4; i++) ctx[b * D_ + tid + i * 256] = 0.f;
    }
}

// K2: fused score GEMM partial — byte-for-byte the R15-measured kernel
// (205 us: 64x128x64 tile, 4 waves 2Mx2N, acc[2][4]=32 AGPR, 2 barriers/step,
// uniform gload_lds staging from pre-converted bf16, XCD-pairing swizzle,
// disjoint per-half partial store). bV dropped (softmax shift-invariant).
// DO NOT MODIFY: 8 schedule/tile variants (R3,R5,R12,R13,R14,R16,R17,R18)
// all regressed against this structure.
__global__ __launch_bounds__(256, 2) void k2_score(
    const unsigned short* __restrict__ Av,
    const unsigned short* __restrict__ W2Th,
    const float* __restrict__ qp,
    const float* __restrict__ b2,
    const float* __restrict__ V,
    float* __restrict__ scorep) {
    __shared__ unsigned short sAh[BM * BK];   // 8 KB
    __shared__ unsigned short sBh[BN * BK];   // 16 KB
    __shared__ float red[2 * BM];

    const int tid = threadIdx.x;
    const int lane = tid & 63;
    const int wid = tid >> 6;
    const int wm = wid >> 1, wn = wid & 1;    // wave tile 32x64
    const int g = lane >> 4, c16 = lane & 15;

    // XCD-pairing swizzle: bid -> wgid (bit rotation, bijective on [0,2048))
    const int bid = blockIdx.x;
    const int wgid = ((bid & 7) << 8) | (bid >> 3);
    const int m0 = (wgid >> 1) * BM;
    const int b = m0 >> 11; // m0 / T_
    const int half = wgid & 1;
    const int nt0 = half * NTP;

    // gload_lds staging mapping (per-wave, 8 rows x 8 chunks per instr)
    const int b_rl = lane >> 3;
    const int b_j = lane & 7;

    float rowpart[8];
    #pragma unroll
    for (int i = 0; i < 8; i++) rowpart[i] = 0.f;

    for (int nt = nt0; nt < nt0 + NTP; nt++) {
        f32x4 acc[2][4];
        #pragma unroll
        for (int mi = 0; mi < 2; mi++)
            #pragma unroll
            for (int ni = 0; ni < 4; ni++) {
                f32x4 z = {0.f, 0.f, 0.f, 0.f};
                acc[mi][ni] = z;
            }

        for (int kt = 0; kt < D_ / BK; kt++) {
            const int k0 = kt * BK;
            __syncthreads(); // previous compute done before LDS overwrite

            // --- B tile: 4 gload_lds/thread from W2T, source pre-swizzled
            #pragma unroll
            for (int i = 0; i < 4; i++) {
                int r = wid * 32 + i * 8 + b_rl;
                int jj = b_j ^ (r & 7);
                size_t soff = (size_t)(nt * BN + r) * D_ + k0 + jj * 8;
                gload_lds16(W2Th + soff, &sBh[(wid * 32 + i * 8) * 64]);
            }
            // --- A tile: 2 gload_lds/thread from Av, source pre-swizzled
            #pragma unroll
            for (int i = 0; i < 2; i++) {
                int r = wid * 16 + i * 8 + b_rl;
                int jj = b_j ^ (r & 7);
                size_t soff = (size_t)(m0 + r) * D_ + k0 + jj * 8;
                gload_lds16(Av + soff, &sAh[(wid * 16 + i * 8) * 64]);
            }

            __syncthreads(); // drains vmcnt (gload_lds)

            #pragma unroll
            for (int s = 0; s < 2; s++) {
                bf16x8 aH[2], bH[4];
                #pragma unroll
                for (int mi = 0; mi < 2; mi++) {
                    int r = wm * 32 + mi * 16 + c16;
                    int idx = r * 64 + (((s * 4 + g) ^ (r & 7)) << 3);
                    aH[mi] = *(const bf16x8*)&sAh[idx];
                }
                #pragma unroll
                for (int ni = 0; ni < 4; ni++) {
                    int r = wn * 64 + ni * 16 + c16;
                    int idx = r * 64 + (((s * 4 + g) ^ (r & 7)) << 3);
                    bH[ni] = *(const bf16x8*)&sBh[idx];
                }
                #pragma unroll
                for (int mi = 0; mi < 2; mi++)
                    #pragma unroll
                    for (int ni = 0; ni < 4; ni++)
                        acc[mi][ni] = __builtin_amdgcn_mfma_f32_16x16x32_bf16(aH[mi], bH[ni], acc[mi][ni], 0, 0, 0);
            }
        }

        // --- epilogue: accumulate V[n]*tanh(acc + qp + b2) into row partials
        #pragma unroll
        for (int ni = 0; ni < 4; ni++) {
            int n = nt * BN + wn * 64 + ni * 16 + c16;
            float qv = qp[b * N_ + n] + b2[n];
            float Vv = V[n];
            #pragma unroll
            for (int mi = 0; mi < 2; mi++)
                #pragma unroll
                for (int r = 0; r < 4; r++) {
                    rowpart[mi * 4 + r] += tanhf(acc[mi][ni][r] + qv) * Vv;
                }
        }
    }

    // reduce across the 16 n-lanes of each group
    #pragma unroll
    for (int i = 0; i < 8; i++) {
        float v = rowpart[i];
        v += __shfl_xor(v, 1);
        v += __shfl_xor(v, 2);
        v += __shfl_xor(v, 4);
        v += __shfl_xor(v, 8);
        rowpart[i] = v;
    }
    if (c16 == 0) {
        #pragma unroll
        for (int mi = 0; mi < 2; mi++)
            #pragma unroll
            for (int r = 0; r < 4; r++)
                red[wn * BM + wm * 32 + mi * 16 + g * 4 + r] = rowpart[mi * 4 + r];
    }
    __syncthreads();
    if (tid < BM) {
        // plain store to this half's disjoint partial buffer (no atomics)
        scorep[(size_t)half * M_ + m0 + tid] = red[tid] + red[BM + tid];
    }
}

// K4: fused softmax + context. Each block recomputes its batch's softmax
// stats from the score partials (deterministic: identical inputs, identical
// reduction order in every block). dc==0 blocks write the weights output;
// all blocks accumulate ctx via atomicAdd (ctx zeroed by k_prep).
__global__ void k4_context(const unsigned short* __restrict__ Av,
                           const float* __restrict__ sp,
                           float* __restrict__ wout,
                           float* __restrict__ ctx) {
    int b = blockIdx.x;
    int dc = blockIdx.y;           // 8 chunks of 128 d
    int tc = blockIdx.z;           // 8 chunks of 256 t
    int tid = threadIdx.x;
    const float* r0 = sp + b * T_;
    const float* r1 = sp + (size_t)M_ + b * T_;

    // --- softmax stats over the full row (8 values/thread)
    float v[8];
    float lmax = -1e30f;
    #pragma unroll
    for (int i = 0; i < 8; i++) {
        int idx = tid + i * 256;
        v[i] = r0[idx] + r1[idx];
        lmax = fmaxf(lmax, v[i]);
    }
    #pragma unroll
    for (int d = 1; d < 64; d <<= 1) lmax = fmaxf(lmax, __shfl_xor(lmax, d));
    __shared__ float sm[4], ss[4];
    if ((tid & 63) == 0) sm[tid >> 6] = lmax;
    __syncthreads();
    lmax = fmaxf(fmaxf(sm[0], sm[1]), fmaxf(sm[2], sm[3]));
    float lsum = 0.f;
    #pragma unroll
    for (int i = 0; i < 8; i++) {
        v[i] = expf(v[i] - lmax);
        lsum += v[i];
    }
    #pragma unroll
    for (int d = 1; d < 64; d <<= 1) lsum += __shfl_xor(lsum, d);
    if ((tid & 63) == 0) ss[tid >> 6] = lsum;
    __syncthreads();
    lsum = ss[0] + ss[1] + ss[2] + ss[3];
    float inv = 1.f / lsum;

    // --- weights output (written once per (b, t) by the dc==0 plane)
    if (dc == 0) wout[b * T_ + tc * 256 + tid] = v[tc] * inv;

    // --- context accumulation over this block's t-slice
    int d4 = tid & 31;
    int th = tid >> 5;             // 8 t-slices of 32
    int d = dc * 128 + d4 * 4;
    const unsigned short* vbase = Av + (size_t)b * T_ * D_ + d;
    float4 acc = {0.f, 0.f, 0.f, 0.f};
    int t0 = tc * 256 + th * 32;
    for (int t = t0; t < t0 + 32; t++) {
        float wt = expf((r0[t] + r1[t]) - lmax) * inv;
        us4 hv = *(const us4*)(vbase + (size_t)t * D_);
        acc.x += wt * __uint_as_float((unsigned)hv[0] << 16);
        acc.y += wt * __uint_as_float((unsigned)hv[1] << 16);
        acc.z += wt * __uint_as_float((unsigned)hv[2] << 16);
        acc.w += wt * __uint_as_float((unsigned)hv[3] << 16);
    }
    __shared__ float4 red4[256];
    red4[threadIdx.x] = acc;
    __syncthreads();
    if (th == 0) {
        float4 s = red4[d4];
        #pragma unroll
        for (int i = 1; i < 8; i++) {
            float4 o = red4[i * 32 + d4];
            s.x += o.x; s.y += o.y; s.z += o.z; s.w += o.w;
        }
        atomicAdd(&ctx[b * D_ + d + 0], s.x);
        atomicAdd(&ctx[b * D_ + d + 1], s.y);
        atomicAdd(&ctx[b * D_ + d + 2], s.z);
        atomicAdd(&ctx[b * D_ + d + 3], s.w);
    }
}

extern "C" void kernel_launch(void* const* d_in, const int* in_sizes, int n_in,
                              void* d_out, int out_size, void* d_ws, size_t ws_size,
                              hipStream_t stream) {
    const float* query  = (const float*)d_in[0];
    const float* values = (const float*)d_in[1];
    const float* W1     = (const float*)d_in[2];
    const float* b1     = (const float*)d_in[3];
    const float* W2     = (const float*)d_in[4];
    const float* b2     = (const float*)d_in[5];
    const float* V      = (const float*)d_in[6];
    // d_in[7] = bV: unused — softmax is shift-invariant, bV affects neither output.

    float* ctx = (float*)d_out;                 // [B, D]
    float* weights = (float*)d_out + B_ * D_;   // [B, T]: written by k4 (dc==0)

    // ws: W2T (2 MB) | q_proj (128 KB) | score partials (512 KB) | Av bf16 (128 MB)
    size_t need = (size_t)N_ * D_ * sizeof(unsigned short)
                + (size_t)B_ * N_ * sizeof(float)
                + (size_t)NTSPLIT * M_ * sizeof(float)
                + (size_t)M_ * D_ * sizeof(unsigned short);
    if (ws_size < need) return;
    unsigned short* Th = (unsigned short*)d_ws;
    float* qp = (float*)(Th + (size_t)N_ * D_);
    float* scorep = qp + (size_t)B_ * N_;
    unsigned short* Av = (unsigned short*)(scorep + (size_t)NTSPLIT * M_);

    k_prep<<<3232, 256, 0, stream>>>(values, Av, W2, Th, query, W1, b1, qp, ctx);
    k2_score<<<(M_ / BM) * NTSPLIT, 256, 0, stream>>>(Av, Th, qp, b2, V, scorep);
    k4_context<<<dim3(B_, 8, 8), 256, 0, stream>>>(Av, scorep, weights, ctx);
}

// Round 20
// 345.988 us; speedup vs baseline: 1.1543x; 1.0162x over previous
//
#include <hip/hip_runtime.h>
#include <hip/hip_bf16.h>

#define B_ 32
#define T_ 2048
#define D_ 1024
#define N_ 1024
#define M_ (B_*T_)

#define BM 64
#define BN 128
#define BK 64
#define NTSPLIT 2                  // two disjoint score-partial buffers, summed in k3
#define NTP (N_ / BN / NTSPLIT)    // 4 nt-passes per block

typedef short bf16x8 __attribute__((ext_vector_type(8)));
typedef float f32x4 __attribute__((ext_vector_type(4)));
typedef unsigned short us4 __attribute__((ext_vector_type(4)));

__device__ __forceinline__ unsigned short bf16_rn(float x) {
    unsigned u = __float_as_uint(x);
    u += 0x7FFFu + ((u >> 16) & 1u);
    return (unsigned short)(u >> 16);
}

__device__ __forceinline__ void gload_lds16(const void* g, void* l) {
    __builtin_amdgcn_global_load_lds(
        (__attribute__((address_space(1))) void*)(g),
        (__attribute__((address_space(3))) void*)(l), 16, 0, 0);
}

// K_prep: fused prologue (R15-verified bodies + R19 ctx-zero branch).
//   blocks [0,2048):    values fp32 -> Av bf16 (RTN)
//   blocks [2048,3072): W2 [D][N] -> W2T bf16 [N][D]
//   blocks [3072,3200): qp[b][n] = query@W1 + b1
//   blocks [3200,3232): zero ctx[b][:] (kills the memsetAsync dispatch)
__global__ void k_prep(const float* __restrict__ values, unsigned short* __restrict__ Av,
                       const float* __restrict__ W2, unsigned short* __restrict__ Th,
                       const float* __restrict__ query, const float* __restrict__ W1,
                       const float* __restrict__ b1, float* __restrict__ qp,
                       float* __restrict__ ctx) {
    __shared__ float tile[32][33];
    const int blk = blockIdx.x;
    const int tid = threadIdx.x;

    if (blk < 2048) {
        size_t base = (size_t)blk * 32768 + (size_t)tid * 8;
        #pragma unroll 4
        for (int it = 0; it < 16; ++it) {
            size_t i = base + (size_t)it * 2048;
            float4 a = *(const float4*)(values + i);
            float4 b = *(const float4*)(values + i + 4);
            us4 h0, h1;
            h0[0] = bf16_rn(a.x); h0[1] = bf16_rn(a.y);
            h0[2] = bf16_rn(a.z); h0[3] = bf16_rn(a.w);
            h1[0] = bf16_rn(b.x); h1[1] = bf16_rn(b.y);
            h1[2] = bf16_rn(b.z); h1[3] = bf16_rn(b.w);
            *(us4*)(Av + i) = h0;
            *(us4*)(Av + i + 4) = h1;
        }
    } else if (blk < 3072) {
        int t = blk - 2048;
        int n0 = (t & 31) * 32, d0 = (t >> 5) * 32;
        int tx = tid & 31, ty = tid >> 5; // 32 x 8
        #pragma unroll
        for (int i = 0; i < 4; i++) {
            int d = d0 + ty + i * 8;
            tile[ty + i * 8][tx] = W2[d * N_ + n0 + tx];
        }
        __syncthreads();
        #pragma unroll
        for (int i = 0; i < 4; i++) {
            int n = n0 + ty + i * 8;
            Th[n * D_ + d0 + tx] = bf16_rn(tile[tx][ty + i * 8]);
        }
    } else if (blk < 3200) {
        int t = blk - 3072;           // 0..127
        int b = t & 31;
        int n = (t >> 5) * 256 + tid; // 4 n-chunks of 256
        const float* q = query + b * D_;
        const float* w = W1 + n;
        float s = 0.f;
        #pragma unroll 8
        for (int d = 0; d < D_; d++) s += q[d] * w[d * N_];
        qp[b * N_ + n] = s + b1[n];
    } else {
        int b = blk - 3200;           // 0..31
        #pragma unroll
        for (int i = 0; i < 4; i++) ctx[b * D_ + tid + i * 256] = 0.f;
    }
}

// K2: fused score GEMM partial — byte-for-byte the R15-measured kernel
// (205 us: 64x128x64 tile, 4 waves 2Mx2N, acc[2][4]=32 AGPR, 2 barriers/step,
// uniform gload_lds staging from pre-converted bf16, XCD-pairing swizzle,
// disjoint per-half partial store). bV dropped (softmax shift-invariant).
// DO NOT MODIFY: 8 schedule/tile variants (R3,R5,R12,R13,R14,R16,R17,R18)
// all regressed against this structure.
__global__ __launch_bounds__(256, 2) void k2_score(
    const unsigned short* __restrict__ Av,
    const unsigned short* __restrict__ W2Th,
    const float* __restrict__ qp,
    const float* __restrict__ b2,
    const float* __restrict__ V,
    float* __restrict__ scorep) {
    __shared__ unsigned short sAh[BM * BK];   // 8 KB
    __shared__ unsigned short sBh[BN * BK];   // 16 KB
    __shared__ float red[2 * BM];

    const int tid = threadIdx.x;
    const int lane = tid & 63;
    const int wid = tid >> 6;
    const int wm = wid >> 1, wn = wid & 1;    // wave tile 32x64
    const int g = lane >> 4, c16 = lane & 15;

    // XCD-pairing swizzle: bid -> wgid (bit rotation, bijective on [0,2048))
    const int bid = blockIdx.x;
    const int wgid = ((bid & 7) << 8) | (bid >> 3);
    const int m0 = (wgid >> 1) * BM;
    const int b = m0 >> 11; // m0 / T_
    const int half = wgid & 1;
    const int nt0 = half * NTP;

    // gload_lds staging mapping (per-wave, 8 rows x 8 chunks per instr)
    const int b_rl = lane >> 3;
    const int b_j = lane & 7;

    float rowpart[8];
    #pragma unroll
    for (int i = 0; i < 8; i++) rowpart[i] = 0.f;

    for (int nt = nt0; nt < nt0 + NTP; nt++) {
        f32x4 acc[2][4];
        #pragma unroll
        for (int mi = 0; mi < 2; mi++)
            #pragma unroll
            for (int ni = 0; ni < 4; ni++) {
                f32x4 z = {0.f, 0.f, 0.f, 0.f};
                acc[mi][ni] = z;
            }

        for (int kt = 0; kt < D_ / BK; kt++) {
            const int k0 = kt * BK;
            __syncthreads(); // previous compute done before LDS overwrite

            // --- B tile: 4 gload_lds/thread from W2T, source pre-swizzled
            #pragma unroll
            for (int i = 0; i < 4; i++) {
                int r = wid * 32 + i * 8 + b_rl;
                int jj = b_j ^ (r & 7);
                size_t soff = (size_t)(nt * BN + r) * D_ + k0 + jj * 8;
                gload_lds16(W2Th + soff, &sBh[(wid * 32 + i * 8) * 64]);
            }
            // --- A tile: 2 gload_lds/thread from Av, source pre-swizzled
            #pragma unroll
            for (int i = 0; i < 2; i++) {
                int r = wid * 16 + i * 8 + b_rl;
                int jj = b_j ^ (r & 7);
                size_t soff = (size_t)(m0 + r) * D_ + k0 + jj * 8;
                gload_lds16(Av + soff, &sAh[(wid * 16 + i * 8) * 64]);
            }

            __syncthreads(); // drains vmcnt (gload_lds)

            #pragma unroll
            for (int s = 0; s < 2; s++) {
                bf16x8 aH[2], bH[4];
                #pragma unroll
                for (int mi = 0; mi < 2; mi++) {
                    int r = wm * 32 + mi * 16 + c16;
                    int idx = r * 64 + (((s * 4 + g) ^ (r & 7)) << 3);
                    aH[mi] = *(const bf16x8*)&sAh[idx];
                }
                #pragma unroll
                for (int ni = 0; ni < 4; ni++) {
                    int r = wn * 64 + ni * 16 + c16;
                    int idx = r * 64 + (((s * 4 + g) ^ (r & 7)) << 3);
                    bH[ni] = *(const bf16x8*)&sBh[idx];
                }
                #pragma unroll
                for (int mi = 0; mi < 2; mi++)
                    #pragma unroll
                    for (int ni = 0; ni < 4; ni++)
                        acc[mi][ni] = __builtin_amdgcn_mfma_f32_16x16x32_bf16(aH[mi], bH[ni], acc[mi][ni], 0, 0, 0);
            }
        }

        // --- epilogue: accumulate V[n]*tanh(acc + qp + b2) into row partials
        #pragma unroll
        for (int ni = 0; ni < 4; ni++) {
            int n = nt * BN + wn * 64 + ni * 16 + c16;
            float qv = qp[b * N_ + n] + b2[n];
            float Vv = V[n];
            #pragma unroll
            for (int mi = 0; mi < 2; mi++)
                #pragma unroll
                for (int r = 0; r < 4; r++) {
                    rowpart[mi * 4 + r] += tanhf(acc[mi][ni][r] + qv) * Vv;
                }
        }
    }

    // reduce across the 16 n-lanes of each group
    #pragma unroll
    for (int i = 0; i < 8; i++) {
        float v = rowpart[i];
        v += __shfl_xor(v, 1);
        v += __shfl_xor(v, 2);
        v += __shfl_xor(v, 4);
        v += __shfl_xor(v, 8);
        rowpart[i] = v;
    }
    if (c16 == 0) {
        #pragma unroll
        for (int mi = 0; mi < 2; mi++)
            #pragma unroll
            for (int r = 0; r < 4; r++)
                red[wn * BM + wm * 32 + mi * 16 + g * 4 + r] = rowpart[mi * 4 + r];
    }
    __syncthreads();
    if (tid < BM) {
        // plain store to this half's disjoint partial buffer (no atomics)
        scorep[(size_t)half * M_ + m0 + tid] = red[tid] + red[BM + tid];
    }
}

// K3: softmax over T per batch: sums the two score partials, softmaxes,
// writes weights (d_out region written only here). R15-measured (~4 us).
__global__ void k3_softmax(const float* __restrict__ sp,
                           float* __restrict__ sw) {
    int b = blockIdx.x;
    const float* r0 = sp + b * T_;
    const float* r1 = sp + (size_t)M_ + b * T_;
    float* row = sw + b * T_;
    int tid = threadIdx.x;
    float v[8];
    float lmax = -1e30f;
    #pragma unroll
    for (int i = 0; i < 8; i++) {
        int idx = tid + i * 256;
        v[i] = r0[idx] + r1[idx];
        lmax = fmaxf(lmax, v[i]);
    }
    #pragma unroll
    for (int d = 1; d < 64; d <<= 1) lmax = fmaxf(lmax, __shfl_xor(lmax, d));
    __shared__ float sm[4], ss[4];
    if ((tid & 63) == 0) sm[tid >> 6] = lmax;
    __syncthreads();
    lmax = fmaxf(fmaxf(sm[0], sm[1]), fmaxf(sm[2], sm[3]));
    float lsum = 0.f;
    #pragma unroll
    for (int i = 0; i < 8; i++) {
        v[i] = expf(v[i] - lmax);
        lsum += v[i];
    }
    #pragma unroll
    for (int d = 1; d < 64; d <<= 1) lsum += __shfl_xor(lsum, d);
    if ((tid & 63) == 0) ss[tid >> 6] = lsum;
    __syncthreads();
    lsum = ss[0] + ss[1] + ss[2] + ss[3];
    float inv = 1.f / lsum;
    #pragma unroll
    for (int i = 0; i < 8; i++) row[tid + i * 256] = v[i] * inv;
}

// K4: context[b][d] += partial over t-slice, reading bf16 Av (half traffic).
// R11/R15-measured (~27 us). (atomic; ctx zeroed by k_prep)
__global__ void k4_context(const unsigned short* __restrict__ Av,
                           const float* __restrict__ w,
                           float* __restrict__ ctx) {
    int b = blockIdx.x;
    int dc = blockIdx.y;           // 8 chunks of 128 d
    int tc = blockIdx.z;           // 8 chunks of 256 t
    int d4 = threadIdx.x & 31;
    int th = threadIdx.x >> 5;     // 8 t-slices of 32
    const float* wrow = w + b * T_;
    int d = dc * 128 + d4 * 4;
    const unsigned short* vbase = Av + (size_t)b * T_ * D_ + d;
    float4 acc = {0.f, 0.f, 0.f, 0.f};
    int t0 = tc * 256 + th * 32;
    for (int t = t0; t < t0 + 32; t++) {
        float wt = wrow[t];
        us4 hv = *(const us4*)(vbase + (size_t)t * D_);
        acc.x += wt * __uint_as_float((unsigned)hv[0] << 16);
        acc.y += wt * __uint_as_float((unsigned)hv[1] << 16);
        acc.z += wt * __uint_as_float((unsigned)hv[2] << 16);
        acc.w += wt * __uint_as_float((unsigned)hv[3] << 16);
    }
    __shared__ float4 red4[256];
    red4[threadIdx.x] = acc;
    __syncthreads();
    if (th == 0) {
        float4 s = red4[d4];
        #pragma unroll
        for (int i = 1; i < 8; i++) {
            float4 o = red4[i * 32 + d4];
            s.x += o.x; s.y += o.y; s.z += o.z; s.w += o.w;
        }
        atomicAdd(&ctx[b * D_ + d + 0], s.x);
        atomicAdd(&ctx[b * D_ + d + 1], s.y);
        atomicAdd(&ctx[b * D_ + d + 2], s.z);
        atomicAdd(&ctx[b * D_ + d + 3], s.w);
    }
}

extern "C" void kernel_launch(void* const* d_in, const int* in_sizes, int n_in,
                              void* d_out, int out_size, void* d_ws, size_t ws_size,
                              hipStream_t stream) {
    const float* query  = (const float*)d_in[0];
    const float* values = (const float*)d_in[1];
    const float* W1     = (const float*)d_in[2];
    const float* b1     = (const float*)d_in[3];
    const float* W2     = (const float*)d_in[4];
    const float* b2     = (const float*)d_in[5];
    const float* V      = (const float*)d_in[6];
    // d_in[7] = bV: unused — softmax is shift-invariant, bV affects neither output.

    float* ctx = (float*)d_out;                 // [B, D]
    float* weights = (float*)d_out + B_ * D_;   // [B, T]: written by k3 only

    // ws: W2T (2 MB) | q_proj (128 KB) | score partials (512 KB) | Av bf16 (128 MB)
    size_t need = (size_t)N_ * D_ * sizeof(unsigned short)
                + (size_t)B_ * N_ * sizeof(float)
                + (size_t)NTSPLIT * M_ * sizeof(float)
                + (size_t)M_ * D_ * sizeof(unsigned short);
    if (ws_size < need) return;
    unsigned short* Th = (unsigned short*)d_ws;
    float* qp = (float*)(Th + (size_t)N_ * D_);
    float* scorep = qp + (size_t)B_ * N_;
    unsigned short* Av = (unsigned short*)(scorep + (size_t)NTSPLIT * M_);

    k_prep<<<3232, 256, 0, stream>>>(values, Av, W2, Th, query, W1, b1, qp, ctx);
    k2_score<<<(M_ / BM) * NTSPLIT, 256, 0, stream>>>(Av, Th, qp, b2, V, scorep);
    k3_softmax<<<B_, 256, 0, stream>>>(scorep, weights);
    k4_context<<<dim3(B_, 8, 8), 256, 0, stream>>>(Av, weights, ctx);
}